// Round 4
// baseline (206.641 us; speedup 1.0000x reference)
//
#include <hip/hip_runtime.h>
#include <hip/hip_bf16.h>
#include <math.h>

// Problem constants
#define BATCH 8192
#define NB 9
#define NN 256
#define PMAX 8
#define HID 32
#define ZDIM 2304   // NB*NN

typedef short bf16x8 __attribute__((ext_vector_type(8)));   // 8 bf16 in 4 VGPRs
typedef float f32x4 __attribute__((ext_vector_type(4)));    // MFMA accumulator

static __device__ inline unsigned short f2bf(float f) {
    __hip_bfloat16 h = __float2bfloat16(f);
    return *reinterpret_cast<unsigned short*>(&h);
}

static __device__ inline uint4 pack8(float4 a, float4 b) {
    uint4 u;
    u.x = (unsigned)f2bf(a.x) | ((unsigned)f2bf(a.y) << 16);
    u.y = (unsigned)f2bf(a.z) | ((unsigned)f2bf(a.w) << 16);
    u.z = (unsigned)f2bf(b.x) | ((unsigned)f2bf(b.y) << 16);
    u.w = (unsigned)f2bf(b.z) | ((unsigned)f2bf(b.w) << 16);
    return u;
}

// ---------------- K0: pack weights to bf16 ------------------------------------
__global__ __launch_bounds__(256) void k_pack(
    const float* __restrict__ W, const float* __restrict__ gW1,
    unsigned short* __restrict__ Wb, unsigned short* __restrict__ WTb,
    unsigned short* __restrict__ gW1b, unsigned short* __restrict__ g1Tb) {
    int r = blockIdx.z;
    int t = threadIdx.x;
    if (r < 8) {
        __shared__ float tt[32][33];
        int i0 = blockIdx.y * 32;
        int j0 = blockIdx.x * 32;
        int tx = t & 31;
        int ty = t >> 5;
        const float* src = W + (size_t)r * 65536;
        #pragma unroll
        for (int s = 0; s < 32; s += 8) {
            float v = src[(size_t)(i0 + ty + s) * 256 + (j0 + tx)];
            tt[ty + s][tx] = v;
            Wb[(size_t)r * 65536 + (size_t)(i0 + ty + s) * 256 + (j0 + tx)] = f2bf(v);
        }
        __syncthreads();
        #pragma unroll
        for (int s = 0; s < 32; s += 8)
            WTb[(size_t)r * 65536 + (size_t)(j0 + ty + s) * 256 + (i0 + tx)] = f2bf(tt[tx][ty + s]);
    } else {
        int tg = (blockIdx.y * 8 + blockIdx.x) * 256 + t;       // 0..16383
        for (int e = tg; e < 73728; e += 16384) {
            float v = gW1[e];
            unsigned short b = f2bf(v);
            gW1b[e] = b;
            int k = e >> 13, n = (e >> 5) & 255, h = e & 31;
            g1Tb[(size_t)(k * 32 + h) * 256 + n] = b;
        }
    }
}

// -------------------- K1 (MFMA): d1[k][b][h] = silu'(a1) * upstream -----------
// Double-buffered L1 loop. Side-product: zb = bf16(z) (full 8192x2304), written
// from the same packed uint4 that goes to LDS -> the GEMM kernel reads bf16.
__global__ __launch_bounds__(256) void k_mlp(
    const float* __restrict__ z, const unsigned short* __restrict__ g1Tb,
    const float* __restrict__ gb1, const float* __restrict__ gW2,
    const float* __restrict__ gb2, const float* __restrict__ gW3,
    float* __restrict__ d1ws, unsigned short* __restrict__ zb) {
    __shared__ uint4 As4[2][512]; // 2 x (128 rows x 32 k bf16); buf0 reused for h1/da2
    __shared__ uint4 Bw[1024];    // gW1^T block: 32 h x 256 n bf16, 8 chunk-regions
    __shared__ uint4 W2Ts4[128];  // W2^T [g][h] bf16 (fragment layout)
    __shared__ uint4 W2Ns4[128];  // W2 natural [h][g] bf16 (fragment layout)

    int t = threadIdx.x;
    int lane = t & 63;
    int w = t >> 6;
    int k = blockIdx.y;
    int b0 = blockIdx.x * 128;

    // ---- stage B (gW1^T) and W2 tiles ----
    const unsigned short* bsrc = g1Tb + (size_t)k * 8192;
    for (int e = t; e < 1024; e += 256) {
        int h = e >> 5;
        int rest = e & 31;
        int c = rest >> 2, qq = rest & 3;
        Bw[c * 128 + (h & 15) + 16 * qq + 64 * (h >> 4)] =
            *(const uint4*)(bsrc + (size_t)h * 256 + c * 32 + qq * 8);
    }
    const float* gw2 = gW2 + (size_t)k * 1024;
    unsigned short* w2t = (unsigned short*)W2Ts4;
    unsigned short* w2n = (unsigned short*)W2Ns4;
    for (int e = t; e < 1024; e += 256) {
        int n = e >> 5, kk = e & 31;
        int qq = kk >> 3, jj = kk & 7;
        int ci = (n & 15) + 16 * qq + 64 * (n >> 4);
        w2t[ci * 8 + jj] = f2bf(gw2[kk * 32 + n]);   // W2T[g=n][h=kk]
        w2n[ci * 8 + jj] = f2bf(gw2[n * 32 + kk]);   // W2N[h=n][g=kk]
    }

    int mq = t >> 2;
    int q = t & 3;
    int ci0 = (mq & 15) + 16 * q + 64 * (mq >> 4);   // pp=0; pp=1 -> +256

    // ---- layer-1 GEMM: acc1 = z_k @ gW1[k] (pipelined) ----
    f32x4 acc1[2][2];
    #pragma unroll
    for (int i = 0; i < 2; ++i)
        #pragma unroll
        for (int j = 0; j < 2; ++j) acc1[i][j] = (f32x4){0.f, 0.f, 0.f, 0.f};

    auto loadZ = [&](int c, float4 (&fa)[2][2]) {
        #pragma unroll
        for (int pp = 0; pp < 2; ++pp) {
            int m = mq + 64 * pp;
            const float* as = z + (size_t)(b0 + m) * ZDIM + k * 256 + c * 32 + q * 8;
            fa[pp][0] = *(const float4*)(as);
            fa[pp][1] = *(const float4*)(as + 4);
        }
    };
    auto sinkZ = [&](int buf, int c, float4 (&fa)[2][2]) {
        #pragma unroll
        for (int pp = 0; pp < 2; ++pp) {
            uint4 pk = pack8(fa[pp][0], fa[pp][1]);
            As4[buf][ci0 + 256 * pp] = pk;
            int m = mq + 64 * pp;
            *(uint4*)(zb + (size_t)(b0 + m) * ZDIM + k * 256 + c * 32 + q * 8) = pk;
        }
    };

    {
        float4 fa[2][2];
        loadZ(0, fa);
        sinkZ(0, 0, fa);
    }
    int cur = 0;
    for (int c = 0; c < 8; ++c) {
        __syncthreads();
        float4 fan[2][2];
        if (c < 7) loadZ(c + 1, fan);
        bf16x8 af[2], bfr[2];
        #pragma unroll
        for (int i = 0; i < 2; ++i) af[i] = __builtin_bit_cast(bf16x8, As4[cur][lane + (w * 2 + i) * 64]);
        #pragma unroll
        for (int j = 0; j < 2; ++j) bfr[j] = __builtin_bit_cast(bf16x8, Bw[c * 128 + lane + j * 64]);
        #pragma unroll
        for (int i = 0; i < 2; ++i)
            #pragma unroll
            for (int j = 0; j < 2; ++j)
                acc1[i][j] = __builtin_amdgcn_mfma_f32_16x16x32_bf16(af[i], bfr[j], acc1[i][j], 0, 0, 0);
        if (c < 7) sinkZ(cur ^ 1, c + 1, fan);
        cur ^= 1;
    }

    // ---- bias + silu; keep silu'(a1); h1 -> LDS buf0 (chunk-swizzled bf16) ----
    int cq = lane >> 4;        // C-layout row quad
    int ci16 = lane & 15;      // C-layout col
    float b1v[2], b2v[2], g3v[2];
    #pragma unroll
    for (int j = 0; j < 2; ++j) {
        b1v[j] = gb1[k * 32 + j * 16 + ci16];
        b2v[j] = gb2[k * 32 + j * 16 + ci16];
        g3v[j] = gW3[k * 32 + j * 16 + ci16];
    }
    unsigned short* Hs = (unsigned short*)As4;
    float sp1[2][2][4];
    __syncthreads();           // all stage-1 As4 reads done
    #pragma unroll
    for (int i = 0; i < 2; ++i)
        #pragma unroll
        for (int j = 0; j < 2; ++j)
            #pragma unroll
            for (int r = 0; r < 4; ++r) {
                float a1 = acc1[i][j][r] + b1v[j];
                float s1 = 1.f / (1.f + __expf(-a1));
                sp1[i][j][r] = s1 * (1.f + a1 * (1.f - s1));
                int row = w * 32 + i * 16 + cq * 4 + r;
                int col = j * 16 + ci16;
                int chunk = (row & 15) + 16 * (col >> 3) + 64 * (row >> 4);
                Hs[chunk * 8 + (col & 7)] = f2bf(a1 * s1);
            }
    __syncthreads();

    // ---- layer-2: a2 = h1 @ W2 ----
    bf16x8 af2[2], wf[2];
    #pragma unroll
    for (int i = 0; i < 2; ++i) af2[i] = __builtin_bit_cast(bf16x8, As4[0][lane + (w * 2 + i) * 64]);
    #pragma unroll
    for (int j = 0; j < 2; ++j) wf[j] = __builtin_bit_cast(bf16x8, W2Ts4[lane + j * 64]);
    f32x4 acc2[2][2];
    #pragma unroll
    for (int i = 0; i < 2; ++i)
        #pragma unroll
        for (int j = 0; j < 2; ++j) {
            acc2[i][j] = (f32x4){0.f, 0.f, 0.f, 0.f};
            acc2[i][j] = __builtin_amdgcn_mfma_f32_16x16x32_bf16(af2[i], wf[j], acc2[i][j], 0, 0, 0);
        }

    // ---- da2 = gW3 * silu'(a2) -> LDS buf0 ----
    __syncthreads();           // h1 reads done
    #pragma unroll
    for (int i = 0; i < 2; ++i)
        #pragma unroll
        for (int j = 0; j < 2; ++j)
            #pragma unroll
            for (int r = 0; r < 4; ++r) {
                float a2 = acc2[i][j][r] + b2v[j];
                float s2 = 1.f / (1.f + __expf(-a2));
                float da2 = g3v[j] * s2 * (1.f + a2 * (1.f - s2));
                int row = w * 32 + i * 16 + cq * 4 + r;
                int col = j * 16 + ci16;
                int chunk = (row & 15) + 16 * (col >> 3) + 64 * (row >> 4);
                Hs[chunk * 8 + (col & 7)] = f2bf(da2);
            }
    __syncthreads();

    // ---- layer-3: dh1 = da2 @ W2^T; d1 = dh1 * silu'(a1) -> global ----
    bf16x8 af3[2], wg[2];
    #pragma unroll
    for (int i = 0; i < 2; ++i) af3[i] = __builtin_bit_cast(bf16x8, As4[0][lane + (w * 2 + i) * 64]);
    #pragma unroll
    for (int j = 0; j < 2; ++j) wg[j] = __builtin_bit_cast(bf16x8, W2Ns4[lane + j * 64]);
    #pragma unroll
    for (int i = 0; i < 2; ++i)
        #pragma unroll
        for (int j = 0; j < 2; ++j) {
            f32x4 a3 = (f32x4){0.f, 0.f, 0.f, 0.f};
            a3 = __builtin_amdgcn_mfma_f32_16x16x32_bf16(af3[i], wg[j], a3, 0, 0, 0);
            #pragma unroll
            for (int r = 0; r < 4; ++r) {
                int row = w * 32 + i * 16 + cq * 4 + r;
                int col = j * 16 + ci16;
                d1ws[((size_t)k * BATCH + b0 + row) * 32 + col] = a3[r] * sp1[i][j][r];
            }
        }
}

// ---- K2 (MFMA, merged): whole output in one launch --------------------------
// id < 1024: lo part — out[:, 0:2048] = -(zb8 @ W[7-k] + d1_k @ gW1[k]^T),
//   128x128 tiles, grid-equivalent (x=64 rows, y=16 cols): same-A col-WGs
//   differ by 64 in id == 0 mod 8 XCDs.
// id >= 1024: hi part — out[:, 2048:] = -(sum_m zb_m @ W[7-m]^T + d1_8 @ gW1[8]^T),
//   64x64 tiles, K-step 64; same-A col-WGs differ by 128 == 0 mod 8.
// All A operands read from zb (bf16): 16B/lane loads, no pack in hot loops.
__global__ __launch_bounds__(256) void k_gemm(
    const unsigned short* __restrict__ zb, const float* __restrict__ d1,
    const unsigned short* __restrict__ Wb, const unsigned short* __restrict__ WTb,
    const unsigned short* __restrict__ gW1b, float* __restrict__ out) {
    __shared__ uint4 As4[2][512];
    __shared__ uint4 Bs4[2][512];

    int id = blockIdx.x;
    int t = threadIdx.x;
    int lane = t & 63;
    int w = t >> 6;

    if (id < 1024) {
        // ---------------- lo part ----------------
        int wr = w >> 1, wc = w & 1;
        int b0 = (id & 63) * 128;
        int n0 = (id >> 6) * 128;
        int k  = n0 >> 8;
        int jb = n0 & 255;

        const unsigned short* Azb = zb + (size_t)b0 * ZDIM + 2048;
        const float* Aext  = d1 + ((size_t)k * BATCH + b0) * 32;
        const unsigned short* Bmain = WTb + (size_t)(7 - k) * 65536 + (size_t)jb * 256;
        const unsigned short* Bext  = gW1b + ((size_t)k * 256 + jb) * 32;

        int mq = t >> 2;
        int q  = t & 3;
        int ci0 = (mq & 15) + 16 * q + 64 * (mq >> 4);

        auto loadAB = [&](int c, uint4 (&au)[2], uint4 (&bu)[2]) {
            #pragma unroll
            for (int pp = 0; pp < 2; ++pp) {
                int m = mq + 64 * pp;
                if (c < 8) {
                    au[pp] = *(const uint4*)(Azb + (size_t)m * ZDIM + c * 32 + q * 8);
                    bu[pp] = *(const uint4*)(Bmain + (size_t)m * 256 + c * 32 + q * 8);
                } else {
                    const float* as = Aext + (size_t)m * 32 + q * 8;
                    au[pp] = pack8(*(const float4*)(as), *(const float4*)(as + 4));
                    bu[pp] = *(const uint4*)(Bext + (size_t)m * 32 + q * 8);
                }
            }
        };
        auto storeAB = [&](int buf, uint4 (&au)[2], uint4 (&bu)[2]) {
            #pragma unroll
            for (int pp = 0; pp < 2; ++pp) {
                int idx = ci0 + 256 * pp;
                As4[buf][idx] = au[pp];
                Bs4[buf][idx] = bu[pp];
            }
        };

        f32x4 acc[4][4];
        #pragma unroll
        for (int i = 0; i < 4; ++i)
            #pragma unroll
            for (int j = 0; j < 4; ++j) acc[i][j] = (f32x4){0.f, 0.f, 0.f, 0.f};

        {
            uint4 au[2], bu[2];
            loadAB(0, au, bu);
            storeAB(0, au, bu);
        }
        int cur = 0;
        for (int c = 0; c < 9; ++c) {
            __syncthreads();
            uint4 aun[2], bun[2];
            if (c < 8) loadAB(c + 1, aun, bun);
            bf16x8 af[4], bf[4];
            #pragma unroll
            for (int i = 0; i < 4; ++i) af[i] = __builtin_bit_cast(bf16x8, As4[cur][lane + (wr * 4 + i) * 64]);
            #pragma unroll
            for (int j = 0; j < 4; ++j) bf[j] = __builtin_bit_cast(bf16x8, Bs4[cur][lane + (wc * 4 + j) * 64]);
            #pragma unroll
            for (int i = 0; i < 4; ++i)
                #pragma unroll
                for (int j = 0; j < 4; ++j)
                    acc[i][j] = __builtin_amdgcn_mfma_f32_16x16x32_bf16(af[i], bf[j], acc[i][j], 0, 0, 0);
            if (c < 8) storeAB(cur ^ 1, aun, bun);
            cur ^= 1;
        }

        int rquad = lane >> 4;
        int cidx  = lane & 15;
        #pragma unroll
        for (int i = 0; i < 4; ++i) {
            #pragma unroll
            for (int j = 0; j < 4; ++j) {
                float* o = out + (size_t)(b0 + wr * 64 + i * 16 + rquad * 4) * ZDIM
                         + (k * 256 + jb + wc * 64 + j * 16 + cidx);
                #pragma unroll
                for (int r = 0; r < 4; ++r)
                    o[(size_t)r * ZDIM] = -acc[i][j][r];
            }
        }
    } else {
        // ---------------- hi part ----------------
        int id2 = id - 1024;
        int wr = w & 1, wc = w >> 1;
        int b0 = (id2 & 127) * 64;
        int i0 = (id2 >> 7) * 64;

        const unsigned short* Azb = zb + (size_t)b0 * ZDIM;
        const float* Aext  = d1 + ((size_t)8 * BATCH + b0) * 32;
        const unsigned short* Bext = gW1b + (size_t)(8 * 256 + i0) * 32;

        int m = t >> 2;
        int q = t & 3;
        int ci = (m & 15) + 16 * q + 64 * (m >> 4);

        auto loadAB = [&](int c, uint4 (&au)[2], uint4 (&bu)[2]) {
            if (c < 32) {
                int kb = c * 64;
                #pragma unroll
                for (int h = 0; h < 2; ++h)
                    au[h] = *(const uint4*)(Azb + (size_t)m * ZDIM + kb + h * 32 + q * 8);
                int lag = kb >> 8;
                int j0  = kb & 255;
                const unsigned short* bs = Wb + (size_t)(7 - lag) * 65536
                                             + (size_t)(i0 + m) * 256 + j0 + q * 8;
                bu[0] = *(const uint4*)(bs);
                bu[1] = *(const uint4*)(bs + 32);
            } else {   // tail: d1_8 (32 valid k) + zero pad
                const float* as = Aext + (size_t)m * 32 + q * 8;
                au[0] = pack8(*(const float4*)(as), *(const float4*)(as + 4));
                au[1] = make_uint4(0u, 0u, 0u, 0u);
                bu[0] = *(const uint4*)(Bext + (size_t)m * 32 + q * 8);
                bu[1] = make_uint4(0u, 0u, 0u, 0u);
            }
        };
        auto storeAB = [&](int buf, uint4 (&au)[2], uint4 (&bu)[2]) {
            #pragma unroll
            for (int h = 0; h < 2; ++h) {
                As4[buf][h * 256 + ci] = au[h];
                Bs4[buf][h * 256 + ci] = bu[h];
            }
        };

        f32x4 acc[2][2];
        #pragma unroll
        for (int i = 0; i < 2; ++i)
            #pragma unroll
            for (int j = 0; j < 2; ++j) acc[i][j] = (f32x4){0.f, 0.f, 0.f, 0.f};

        {
            uint4 au[2], bu[2];
            loadAB(0, au, bu);
            storeAB(0, au, bu);
        }
        int cur = 0;
        for (int c = 0; c < 33; ++c) {
            __syncthreads();
            uint4 aun[2], bun[2];
            if (c < 32) loadAB(c + 1, aun, bun);
            #pragma unroll
            for (int h = 0; h < 2; ++h) {
                bf16x8 af[2], bf[2];
                #pragma unroll
                for (int i = 0; i < 2; ++i)
                    af[i] = __builtin_bit_cast(bf16x8, As4[cur][h * 256 + lane + (wr * 2 + i) * 64]);
                #pragma unroll
                for (int j = 0; j < 2; ++j)
                    bf[j] = __builtin_bit_cast(bf16x8, Bs4[cur][h * 256 + lane + (wc * 2 + j) * 64]);
                #pragma unroll
                for (int i = 0; i < 2; ++i)
                    #pragma unroll
                    for (int j = 0; j < 2; ++j)
                        acc[i][j] = __builtin_amdgcn_mfma_f32_16x16x32_bf16(af[i], bf[j], acc[i][j], 0, 0, 0);
            }
            if (c < 32) storeAB(cur ^ 1, aun, bun);
            cur ^= 1;
        }

        int rquad = lane >> 4;
        int cidx  = lane & 15;
        #pragma unroll
        for (int i = 0; i < 2; ++i) {
            #pragma unroll
            for (int j = 0; j < 2; ++j) {
                float* o = out + (size_t)(b0 + wr * 32 + i * 16 + rquad * 4) * ZDIM
                         + (2048 + i0 + wc * 32 + j * 16 + cidx);
                #pragma unroll
                for (int r = 0; r < 4; ++r)
                    o[(size_t)r * ZDIM] = -acc[i][j][r];
            }
        }
    }
}

extern "C" void kernel_launch(void* const* d_in, const int* in_sizes, int n_in,
                              void* d_out, int out_size, void* d_ws, size_t ws_size,
                              hipStream_t stream) {
    const float* z   = (const float*)d_in[0];
    const float* gW1 = (const float*)d_in[1];
    const float* gb1 = (const float*)d_in[2];
    const float* gW2 = (const float*)d_in[3];
    const float* gb2 = (const float*)d_in[4];
    const float* gW3 = (const float*)d_in[5];
    // d_in[6] = gb3: constant, no grad
    const float* W   = (const float*)d_in[7];
    float* out = (float*)d_out;

    float* ws = (float*)d_ws;
    float*          d1ws = ws;                               // 2359296 f32 (9.4 MB)
    unsigned short* Wb   = (unsigned short*)(ws + 2359296);  // 524288 bf16
    unsigned short* WTb  = Wb + 524288;                      // 524288 bf16
    unsigned short* gW1b = WTb + 524288;                     // 73728 bf16
    unsigned short* g1Tb = gW1b + 73728;                     // 73728 bf16
    unsigned short* zb   = g1Tb + 73728;                     // 18874368 bf16 (37.7 MB; ~49.6 MB total)

    k_pack<<<dim3(8, 8, 9), 256, 0, stream>>>(W, gW1, Wb, WTb, gW1b, g1Tb);
    k_mlp<<<dim3(64, 9), 256, 0, stream>>>(z, g1Tb, gb1, gW2, gb2, gW3, d1ws, zb);
    k_gemm<<<dim3(1536), 256, 0, stream>>>(zb, d1ws, Wb, WTb, gW1b, out);
}